// Round 14
// baseline (160.924 us; speedup 1.0000x reference)
//
#include <hip/hip_runtime.h>
#include <hip/hip_bf16.h>

// B=1, S=4096, D=4096, O=4096
//   q = fake-quant(x) per row (int8 levels, scale = 127/max(|x|,1e-5))
//   out[s,o] = (sum_d qi[s,d]*W[o,d]) * rscale[s]/ws + bias[o]/ws
// qi in [-128,127], W in {-1,0,1}: i8 MFMA with i32 accum is EXACT (|sum|<2^19).
//
// R14: break the LDS-read/MFMA pipe serialization (R10: 1152 cyc LDS reads +
// 1307 cyc MFMA serialize per tile). A-fragments now load GLOBAL->VGPR
// directly (reg double-buffer, L2-resident panels); only B is LDS-staged
// (ring-3, verified 0-conflict layout). LDS reads/tile/CU: 96 -> 32.

#define SEQ  4096
#define DIM  4096
#define OUTD 4096

typedef int i32x4 __attribute__((ext_vector_type(4)));
typedef unsigned char u8;

__device__ __forceinline__ void gload16(const void* g, void* lds) {
    __builtin_amdgcn_global_load_lds(
        (const __attribute__((address_space(1))) void*)g,
        (__attribute__((address_space(3))) void*)lds, 16, 0, 0);
}

// Verified conflict-free layout (R2/R3/R5/R6/R10: SQ_LDS_BANK_CONFLICT == 0):
// 256 rows x 64B (i8), 128 row-pairs of 128B; element (r, 16B-quarter kq) at
//   (r>>1)*128 + ((((r&1)<<6) | (kq<<4)) ^ (((r>>1)&3)<<4))
__device__ __forceinline__ int ldsoff(int r, int kq) {
    const int rp = r >> 1;
    const int w = (((r & 1) << 6) | (kq << 4)) ^ ((rp & 3) << 4);
    return rp * 128 + w;
}

// ---------------- Kernel 1: fused prep (quant rows | W conversion) ----------------
__global__ __launch_bounds__(256) void prep_kernel(
    const float* __restrict__ x, char* __restrict__ q, float* __restrict__ rscale,
    const float4* __restrict__ W4, char4* __restrict__ Wb4) {
    const int bid = blockIdx.x;
    const int t = threadIdx.x;
    if (bid < SEQ) {
        const int row = bid;
        const int lane = t & 63, wave = t >> 6;
        const float4* xr = (const float4*)(x + (size_t)row * DIM);
        float4 r[4];
        float m = 0.0f;
#pragma unroll
        for (int i = 0; i < 4; ++i) {
            r[i] = xr[t + 256 * i];
            m = fmaxf(m, fmaxf(fmaxf(fabsf(r[i].x), fabsf(r[i].y)),
                               fmaxf(fabsf(r[i].z), fabsf(r[i].w))));
        }
#pragma unroll
        for (int off = 32; off > 0; off >>= 1)
            m = fmaxf(m, __shfl_xor(m, off, 64));
        __shared__ float red[4];
        if (lane == 0) red[wave] = m;
        __syncthreads();
        const float amax = fmaxf(fmaxf(red[0], red[1]), fmaxf(red[2], red[3]));
        const float scale = 127.0f / fmaxf(amax, 1e-5f);
        if (t == 0) rscale[row] = 1.0f / scale;
        char4* qr = (char4*)(q + (size_t)row * DIM);
#pragma unroll
        for (int i = 0; i < 4; ++i) {
            float q0 = fminf(127.0f, fmaxf(-128.0f, rintf(r[i].x * scale)));
            float q1 = fminf(127.0f, fmaxf(-128.0f, rintf(r[i].y * scale)));
            float q2 = fminf(127.0f, fmaxf(-128.0f, rintf(r[i].z * scale)));
            float q3 = fminf(127.0f, fmaxf(-128.0f, rintf(r[i].w * scale)));
            char4 o;
            o.x = (signed char)q0; o.y = (signed char)q1;
            o.z = (signed char)q2; o.w = (signed char)q3;
            qr[t + 256 * i] = o;
        }
    } else {
        const int n4 = (OUTD * DIM) / 4;
        int i = (bid - SEQ) * 256 + t;
        const int stride = SEQ * 256;
        for (; i < n4; i += stride) {
            float4 w = W4[i];
            char4 o;
            o.x = (signed char)w.x; o.y = (signed char)w.y;
            o.z = (signed char)w.z; o.w = (signed char)w.w;
            Wb4[i] = o;
        }
    }
}

// ---------------- Kernel 2: A-in-reg, B-in-LDS(ring-3) i8 GEMM ----------------
__global__ __launch_bounds__(512, 2) void gemm_kernel(
    const u8* __restrict__ A, const u8* __restrict__ B,
    const float* __restrict__ rscale, const float* __restrict__ bias,
    const float* __restrict__ wscale, float* __restrict__ out) {
    __shared__ __align__(16) u8 Bs[3 * 16384];   // B ring-3 (48KB)
    const int tid = threadIdx.x;
    const int lane = tid & 63, wave = tid >> 6;
    const int wr = wave >> 2, wc = wave & 3;       // 2 x 4 waves, 128x64 per wave
    const int fr = lane & 15, kq = lane >> 4;

    // bijective XCD swizzle (256 % 8 == 0)
    const int bid = blockIdx.x;
    const int swz = (bid & 7) * 32 + (bid >> 3);
    const int brow = swz >> 4, bcol = swz & 15;

    // B staging: LDS dest linear (thread t -> bytes t*16 of each 8KB chunk);
    // inverse swizzle applied to GLOBAL source (involution). Verified R2-R13.
    const int v = (tid & 7) ^ ((tid >> 3) & 3);
    const int kb = (v & 3) * 16;
    const int r0 = ((tid >> 3) << 1) + (v >> 2);
    const u8* gB0 = B + (size_t)(bcol * 256 + r0) * DIM + kb;
    const u8* gB1 = B + (size_t)(bcol * 256 + 128 + r0) * DIM + kb;
    u8* lB0 = &Bs[tid * 16];
    u8* lB1 = &Bs[8192 + tid * 16];

#define STAGEB(T, S) do { const int _k = (T) * 64;         \
        gload16(gB0 + _k, lB0 + (S) * 16384);              \
        gload16(gB1 + _k, lB1 + (S) * 16384); } while (0)

    // A fragment pointers: lane holds A[row=wr*128+m*16+fr][k=t*64+kq*16 ..+16)
    const u8* gAm[8];
#pragma unroll
    for (int m = 0; m < 8; ++m)
        gAm[m] = A + (size_t)(brow * 256 + wr * 128 + m * 16 + fr) * DIM + kq * 16;

#define LOADA(DST, T) do { const int _k = (T) * 64;        \
        _Pragma("unroll")                                  \
        for (int m = 0; m < 8; ++m)                        \
            DST[m] = *(const i32x4*)(gAm[m] + _k); } while (0)

    int boff[4];
#pragma unroll
    for (int n = 0; n < 4; ++n) boff[n] = ldsoff(wc * 64 + n * 16 + fr, kq);

    i32x4 acc[8][4] = {};

#define VMW(N) asm volatile("s_waitcnt vmcnt(" #N ")" ::: "memory")
#define BAR()  do { asm volatile("" ::: "memory");                             \
                    __builtin_amdgcn_s_barrier();                              \
                    asm volatile("" ::: "memory"); } while (0)

// One K-tile: wait B(T) (vmcnt(10): only stage(T+1)[2]+A(T)[8] are newer),
// barrier; read B frags; stage B(T+2); load A(T+1) regs; 32 MFMAs on A(T)
// (compiler inserts exact counted vmcnt/lgkmcnt before consumers).
#define ITER(CUR, NXT, T, SL, SS, DO_STAGE, DO_LOAD) do {                      \
        VMW(10); BAR();                                                        \
        i32x4 bfv[4];                                                          \
        _Pragma("unroll")                                                      \
        for (int n = 0; n < 4; ++n)                                            \
            bfv[n] = *(const i32x4*)&Bs[(SL) * 16384 + boff[n]];               \
        if (DO_STAGE) STAGEB((T) + 2, SS);                                     \
        if (DO_LOAD) LOADA(NXT, (T) + 1);                                      \
        _Pragma("unroll")                                                      \
        for (int m = 0; m < 8; ++m)                                            \
            _Pragma("unroll")                                                  \
            for (int n = 0; n < 4; ++n)                                        \
                acc[m][n] = __builtin_amdgcn_mfma_i32_16x16x64_i8(             \
                    CUR[m], bfv[n], acc[m][n], 0, 0, 0);                       \
    } while (0)

    i32x4 afA[8], afB[8];

    // prologue: B(0),B(1) staged; A(0) in regs
    STAGEB(0, 0); STAGEB(1, 1);
    LOADA(afA, 0);

    // 64 K-tiles; slot = t%3, A-set alternates per tile (period lcm=6)
    for (int tb = 0; tb < 10; ++tb) {
        const int t = tb * 6;
        ITER(afA, afB, t + 0, 0, 2, 1, 1);
        ITER(afB, afA, t + 1, 1, 0, 1, 1);
        ITER(afA, afB, t + 2, 2, 1, 1, 1);
        ITER(afB, afA, t + 3, 0, 2, 1, 1);
        ITER(afA, afB, t + 4, 1, 0, 1, 1);
        ITER(afB, afA, t + 5, 2, 1, 1, 1);
    }
    // tail: t=60..63
    ITER(afA, afB, 60, 0, 2, 1, 1);   // stage 62, load A(61)
    ITER(afB, afA, 61, 1, 0, 1, 1);   // stage 63, load A(62)
    ITER(afA, afB, 62, 2, 0, 0, 1);   // load A(63)
    VMW(0); BAR();
    {
        i32x4 bfv[4];
#pragma unroll
        for (int n = 0; n < 4; ++n)
            bfv[n] = *(const i32x4*)&Bs[0 * 16384 + boff[n]];
#pragma unroll
        for (int m = 0; m < 8; ++m)
#pragma unroll
            for (int n = 0; n < 4; ++n)
                acc[m][n] = __builtin_amdgcn_mfma_i32_16x16x64_i8(
                    afB[m], bfv[n], acc[m][n], 0, 0, 0);
    }

    // epilogue: C/D layout col=lane&15, row=(lane>>4)*4+j (dtype-independent)
    const float invws = 1.0f / wscale[0];
    const int rr0 = brow * 256 + wr * 128 + (kq << 2);
    const int c0 = bcol * 256 + wc * 64 + fr;
    float bv[4];
#pragma unroll
    for (int n = 0; n < 4; ++n) bv[n] = bias[c0 + n * 16] * invws;
#pragma unroll
    for (int m = 0; m < 8; ++m) {
#pragma unroll
        for (int j = 0; j < 4; ++j) {
            const int r = rr0 + m * 16 + j;
            const float rs = rscale[r] * invws;
            float* orow = out + (size_t)r * OUTD + c0;
#pragma unroll
            for (int n = 0; n < 4; ++n)
                orow[n * 16] = (float)acc[m][n][j] * rs + bv[n];
        }
    }
#undef STAGEB
#undef LOADA
#undef ITER
#undef VMW
#undef BAR
}

extern "C" void kernel_launch(void* const* d_in, const int* in_sizes, int n_in,
                              void* d_out, int out_size, void* d_ws, size_t ws_size,
                              hipStream_t stream) {
    const float* x      = (const float*)d_in[0];
    const float* W      = (const float*)d_in[1];
    const float* bias   = (const float*)d_in[2];
    const float* wscale = (const float*)d_in[3];
    float* out = (float*)d_out;

    char* ws = (char*)d_ws;
    char* q_i8 = ws;                                   // 16 MB
    char* w_i8 = ws + (size_t)16777216;                // 16 MB
    float* rscale = (float*)(ws + (size_t)33554432);   // 16 KB

    prep_kernel<<<SEQ + 4096, 256, 0, stream>>>(
        x, q_i8, rscale, (const float4*)W, (char4*)w_i8);
    gemm_kernel<<<256, 512, 0, stream>>>((const u8*)q_i8, (const u8*)w_i8,
                                         rscale, bias, wscale, out);
}

// Round 15
// 90.474 us; speedup vs baseline: 1.7787x; 1.7787x over previous
//
#include <hip/hip_runtime.h>
#include <hip/hip_bf16.h>

// B=1, S=4096, D=4096, O=4096
//   q = fake-quant(x) per row (int8 levels, scale = 127/max(|x|,1e-5))
//   out[s,o] = (sum_d qi[s,d]*W[o,d]) * rscale[s]/ws + bias[o]/ws
// qi in [-128,127], W in {-1,0,1}: i8 MFMA with i32 accum is EXACT (|sum|<2^19).
//
// R15 = R10 restored (verified best: 92.5 us total, GEMM 69.9 us):
//  - GEMM: 256x256 tile, BK=64, mfma_i32_16x16x64_i8, ring-4 LDS, counted
//    VMW(8), 1 barrier/tile, monolithic body, 0-conflict swizzled LDS.
//    Best of 12 structural variants (R4-R14 all null/negative).
//  - prep: fused single launch (BW-bound at its 160MB floor).

#define SEQ  4096
#define DIM  4096
#define OUTD 4096

typedef int i32x4 __attribute__((ext_vector_type(4)));
typedef unsigned char u8;

__device__ __forceinline__ void gload16(const void* g, void* lds) {
    __builtin_amdgcn_global_load_lds(
        (const __attribute__((address_space(1))) void*)g,
        (__attribute__((address_space(3))) void*)lds, 16, 0, 0);
}

// Verified conflict-free layout (R2/R3/R5/R6/R8/R10/R13: SQ_LDS_BANK_CONFLICT==0):
// 256 rows x 64B (i8), 128 row-pairs of 128B; element (r, 16B-quarter kq) at
//   (r>>1)*128 + ((((r&1)<<6) | (kq<<4)) ^ (((r>>1)&3)<<4))
__device__ __forceinline__ int ldsoff(int r, int kq) {
    const int rp = r >> 1;
    const int w = (((r & 1) << 6) | (kq << 4)) ^ ((rp & 3) << 4);
    return rp * 128 + w;
}

// ---------------- Kernel 1: fused prep (quant rows | W conversion) ----------------
__global__ __launch_bounds__(256) void prep_kernel(
    const float* __restrict__ x, char* __restrict__ q, float* __restrict__ rscale,
    const float4* __restrict__ W4, char4* __restrict__ Wb4) {
    const int bid = blockIdx.x;
    const int t = threadIdx.x;
    if (bid < SEQ) {
        const int row = bid;
        const int lane = t & 63, wave = t >> 6;
        const float4* xr = (const float4*)(x + (size_t)row * DIM);
        float4 r[4];
        float m = 0.0f;
#pragma unroll
        for (int i = 0; i < 4; ++i) {
            r[i] = xr[t + 256 * i];
            m = fmaxf(m, fmaxf(fmaxf(fabsf(r[i].x), fabsf(r[i].y)),
                               fmaxf(fabsf(r[i].z), fabsf(r[i].w))));
        }
#pragma unroll
        for (int off = 32; off > 0; off >>= 1)
            m = fmaxf(m, __shfl_xor(m, off, 64));
        __shared__ float red[4];
        if (lane == 0) red[wave] = m;
        __syncthreads();
        const float amax = fmaxf(fmaxf(red[0], red[1]), fmaxf(red[2], red[3]));
        const float scale = 127.0f / fmaxf(amax, 1e-5f);
        if (t == 0) rscale[row] = 1.0f / scale;
        char4* qr = (char4*)(q + (size_t)row * DIM);
#pragma unroll
        for (int i = 0; i < 4; ++i) {
            float q0 = fminf(127.0f, fmaxf(-128.0f, rintf(r[i].x * scale)));
            float q1 = fminf(127.0f, fmaxf(-128.0f, rintf(r[i].y * scale)));
            float q2 = fminf(127.0f, fmaxf(-128.0f, rintf(r[i].z * scale)));
            float q3 = fminf(127.0f, fmaxf(-128.0f, rintf(r[i].w * scale)));
            char4 o;
            o.x = (signed char)q0; o.y = (signed char)q1;
            o.z = (signed char)q2; o.w = (signed char)q3;
            qr[t + 256 * i] = o;
        }
    } else {
        const int n4 = (OUTD * DIM) / 4;
        int i = (bid - SEQ) * 256 + t;
        const int stride = SEQ * 256;
        for (; i < n4; i += stride) {
            float4 w = W4[i];
            char4 o;
            o.x = (signed char)w.x; o.y = (signed char)w.y;
            o.z = (signed char)w.z; o.w = (signed char)w.w;
            Wb4[i] = o;
        }
    }
}

// ---------------- Kernel 2: ring-4 pipelined i8 GEMM (R3-exact), fused epilogue ----
__global__ __launch_bounds__(512, 2) void gemm_kernel(
    const u8* __restrict__ A, const u8* __restrict__ B,
    const float* __restrict__ rscale, const float* __restrict__ bias,
    const float* __restrict__ wscale, float* __restrict__ out) {
    __shared__ __align__(16) u8 As[4 * 16384];   // 4 slots x 16KB
    __shared__ __align__(16) u8 Bs[4 * 16384];
    const int tid = threadIdx.x;
    const int lane = tid & 63, wave = tid >> 6;
    const int wr = wave >> 2, wc = wave & 3;       // 2 x 4 waves, 128x64 per wave
    const int fr = lane & 15, kq = lane >> 4;

    // bijective XCD swizzle (256 % 8 == 0)
    const int bid = blockIdx.x;
    const int swz = (bid & 7) * 32 + (bid >> 3);
    const int brow = swz >> 4, bcol = swz & 15;

    // staging: LDS dest linear (thread t -> bytes t*16 of each 8KB chunk);
    // inverse swizzle applied to the GLOBAL source (involution). Verified R2-R13.
    const int v = (tid & 7) ^ ((tid >> 3) & 3);
    const int kb = (v & 3) * 16;                   // byte offset within 64B row
    const int r0 = ((tid >> 3) << 1) + (v >> 2);   // chunk0 tile-row
    const u8* gA0 = A + (size_t)(brow * 256 + r0) * DIM + kb;
    const u8* gA1 = A + (size_t)(brow * 256 + 128 + r0) * DIM + kb;
    const u8* gB0 = B + (size_t)(bcol * 256 + r0) * DIM + kb;
    const u8* gB1 = B + (size_t)(bcol * 256 + 128 + r0) * DIM + kb;
    u8* lA0 = &As[tid * 16];
    u8* lA1 = &As[8192 + tid * 16];
    u8* lB0 = &Bs[tid * 16];
    u8* lB1 = &Bs[8192 + tid * 16];

#define STAGE(T, S) do { const int _k = (T) * 64;          \
        gload16(gA0 + _k, lA0 + (S) * 16384);              \
        gload16(gA1 + _k, lA1 + (S) * 16384);              \
        gload16(gB0 + _k, lB0 + (S) * 16384);              \
        gload16(gB1 + _k, lB1 + (S) * 16384); } while (0)

    int aoff[8], boff[4];
#pragma unroll
    for (int m = 0; m < 8; ++m) aoff[m] = ldsoff(wr * 128 + m * 16 + fr, kq);
#pragma unroll
    for (int n = 0; n < 4; ++n) boff[n] = ldsoff(wc * 64 + n * 16 + fr, kq);

    i32x4 acc[8][4] = {};

#define COMPUTE(S) do {                                                        \
        i32x4 af[8], bfv[4];                                                   \
        _Pragma("unroll")                                                      \
        for (int n = 0; n < 4; ++n)                                            \
            bfv[n] = *(const i32x4*)&Bs[(S) * 16384 + boff[n]];                \
        _Pragma("unroll")                                                      \
        for (int m = 0; m < 8; ++m)                                            \
            af[m] = *(const i32x4*)&As[(S) * 16384 + aoff[m]];                 \
        _Pragma("unroll")                                                      \
        for (int m = 0; m < 8; ++m)                                            \
            _Pragma("unroll")                                                  \
            for (int n = 0; n < 4; ++n)                                        \
                acc[m][n] = __builtin_amdgcn_mfma_i32_16x16x64_i8(             \
                    af[m], bfv[n], acc[m][n], 0, 0, 0);                        \
    } while (0)

#define VMW(N) asm volatile("s_waitcnt vmcnt(" #N ")" ::: "memory")
#define BAR()  do { asm volatile("" ::: "memory");                             \
                    __builtin_amdgcn_s_barrier();                              \
                    asm volatile("" ::: "memory"); } while (0)

    // 64 K-tiles of BK=64. Prologue: tiles 0..2 in flight.
    STAGE(0, 0); STAGE(1, 1); STAGE(2, 2);

    for (int tb = 0; tb < 15; ++tb) {
        const int t = tb * 4;
        VMW(8); BAR(); STAGE(t + 3, 3); COMPUTE(0);
        VMW(8); BAR(); STAGE(t + 4, 0); COMPUTE(1);
        VMW(8); BAR(); STAGE(t + 5, 1); COMPUTE(2);
        VMW(8); BAR(); STAGE(t + 6, 2); COMPUTE(3);
    }
    // tail: tiles 60..63
    VMW(8); BAR(); STAGE(63, 3); COMPUTE(0);
    VMW(8); BAR(); COMPUTE(1);
    VMW(4); BAR(); COMPUTE(2);
    VMW(0); BAR(); COMPUTE(3);

    // epilogue: C/D layout col=lane&15, row=(lane>>4)*4+j (dtype-independent)
    const float invws = 1.0f / wscale[0];
    const int rr0 = brow * 256 + wr * 128 + (kq << 2);
    const int c0 = bcol * 256 + wc * 64 + fr;
    float bv[4];
#pragma unroll
    for (int n = 0; n < 4; ++n) bv[n] = bias[c0 + n * 16] * invws;
#pragma unroll
    for (int m = 0; m < 8; ++m) {
#pragma unroll
        for (int j = 0; j < 4; ++j) {
            const int r = rr0 + m * 16 + j;
            const float rs = rscale[r] * invws;
            float* orow = out + (size_t)r * OUTD + c0;
#pragma unroll
            for (int n = 0; n < 4; ++n)
                orow[n * 16] = (float)acc[m][n][j] * rs + bv[n];
        }
    }
#undef STAGE
#undef COMPUTE
#undef VMW
#undef BAR
}

extern "C" void kernel_launch(void* const* d_in, const int* in_sizes, int n_in,
                              void* d_out, int out_size, void* d_ws, size_t ws_size,
                              hipStream_t stream) {
    const float* x      = (const float*)d_in[0];
    const float* W      = (const float*)d_in[1];
    const float* bias   = (const float*)d_in[2];
    const float* wscale = (const float*)d_in[3];
    float* out = (float*)d_out;

    char* ws = (char*)d_ws;
    char* q_i8 = ws;                                   // 16 MB
    char* w_i8 = ws + (size_t)16777216;                // 16 MB
    float* rscale = (float*)(ws + (size_t)33554432);   // 16 KB

    prep_kernel<<<SEQ + 4096, 256, 0, stream>>>(
        x, q_i8, rscale, (const float4*)W, (char4*)w_i8);
    gemm_kernel<<<256, 512, 0, stream>>>((const u8*)q_i8, (const u8*)w_i8,
                                         rscale, bias, wscale, out);
}